// Round 7
// baseline (498.105 us; speedup 1.0000x reference)
//
#include <hip/hip_runtime.h>

#define T_DIM 16384
#define H_DIM 2048
#define I_DIM 1408
#define NB_DIM (2 * I_DIM)   // 2816 interleaved gate/up columns

typedef _Float16 half8 __attribute__((ext_vector_type(8)));
typedef float floatx4 __attribute__((ext_vector_type(4)));

// -------- async global -> LDS, 16 bytes per lane (gfx950) --------
__device__ __forceinline__ void async_cp16(const _Float16* gp, _Float16* lp) {
    __builtin_amdgcn_global_load_lds(
        (const __attribute__((address_space(1))) unsigned int*)gp,
        (__attribute__((address_space(3))) unsigned int*)lp,
        16, 0, 0);
}

// -------- fp32 -> fp16 conversion of x --------
__global__ void cvt_fp16_kernel(const float* __restrict__ x, _Float16* __restrict__ xh) {
    int i = (blockIdx.x * 256 + threadIdx.x) * 8;
    const float4* p = (const float4*)(x + i);
    float4 a = p[0];
    float4 b = p[1];
    half8 o = { (_Float16)a.x, (_Float16)a.y, (_Float16)a.z, (_Float16)a.w,
                (_Float16)b.x, (_Float16)b.y, (_Float16)b.z, (_Float16)b.w };
    *(half8*)(xh + i) = o;
}

// -------- GPTQ dequant -> transposed fp16 weight Wt[n'][k] (unchanged, verified) --------
__global__ void dequant_kernel(const int* __restrict__ qw, const int* __restrict__ qz,
                               const float* __restrict__ sc, _Float16* __restrict__ Wt,
                               int K, int N, int interleave, int off) {
    __shared__ half8 tile[256];
    int t = threadIdx.x;
    int nl = t & 63, kl = t >> 6;
    int n  = blockIdx.x * 64 + nl;
    int kp = blockIdx.y * 4 + kl;
    int q = qw[kp * N + n];
    int g = kp >> 4;
    float scale = sc[g * N + n];
    int zq = (qz[g * (N >> 3) + (n >> 3)] >> (4 * (n & 7))) & 0xF;
    float zf = (float)(zq + 1);
    half8 o;
#pragma unroll
    for (int j = 0; j < 8; ++j)
        o[j] = (_Float16)(((float)((q >> (4 * j)) & 0xF) - zf) * scale);
    tile[nl * 4 + kl] = o;
    __syncthreads();
    int nl2 = t >> 2, kl2 = t & 3;
    int n2 = blockIdx.x * 64 + nl2;
    int np = interleave ? (((n2 >> 5) << 6) + (n2 & 31) + off) : n2;
    *(half8*)(Wt + (size_t)np * K + (size_t)(blockIdx.y * 4 + kl2) * 8) = tile[nl2 * 4 + kl2];
}

// ============ 256x256 GEMM, BK=64, 512 thr, 128 KiB LDS, read-ahead pipeline ============
// ROW-REGION MAP (round-6 fix): wave (wm,wn); A quadrant (wm,mh) = rows wm*128+mh*64+[0,64);
// B quadrant (wn,nh) = rows wn*64+nh*32+[0,32). So ph3's READ_A(·,0) touches rows
// {0-63,128-191} (parts of BOTH stage halves) and READ_B touches all B rows.
// => A is staged by ROW-GROUP, not by half: STAGE_A2(sub) = rows {sub*64..+63} of both
// halves (2 loads: LDS dests sub*4096 and 8192+sub*4096 halves).
// Publish requirements:  by ph3(t-1): A.0(t) [rows 0-63,128-191], B0(t), B1(t);
//                        by ph1(t):   A.1(t) [rows 64-127,192-255].
// Stage slots in TILE(p,t) -> buf p^1, tile t+1:  ph0: A.0  ph1: B0+B1  ph2: A.1.
// Issue stream: ..., A.0(t+1), B0(t+1), B1(t+1), A.1(t+1), A.0(t+2), ...
// Waits (after MFMA, before next phase's BAR where applicable):
//   ph1: vmcnt(6) -> drains A.1(t)          ph3: vmcnt(2) -> drains A.0,B0,B1(t+1)
// Peak 8 VMEM outstanding; never drained to 0 in the main loop.
// ds_reads issued one+ phase ahead of use:
//   ph3(t-1) post-MFMA: A-quad0 + both B halves of t (16 reads)
//   ph1(t)  post-MFMA: A-quad1 of t (8 reads)
// lgkm: ph0 LG(4) (bf[1] may fly), else LG(0) — all reads hidden behind >=1 barrier+MFMA.
// All waits/ds_reads carry "memory" clobbers (round-5 lesson: global_load_lds must not
// migrate across counted vmcnt); sched_barrier(0) after waits pins MFMA (rule #18).

#define STAGE_A2(pp, sub, kt) do {                                                    \
    async_cp16(ag + (size_t)((sub) * 64) * KDIM + (size_t)(kt) * 64,                  \
               &As[pp][(sub) * 4096 + ldst]);                                         \
    async_cp16(ag + (size_t)(128 + (sub) * 64) * KDIM + (size_t)(kt) * 64,            \
               &As[pp][8192 + (sub) * 4096 + ldst]);                                  \
} while (0)

#define STAGE_B(pp, h, kt) do {                                                       \
    async_cp16(bg + (size_t)((h) * 128) * KDIM + (size_t)(kt) * 64,                   \
               &Bs[pp][(h) * 8192 + ldst]);                                           \
    async_cp16(bg + (size_t)((h) * 128 + 64) * KDIM + (size_t)(kt) * 64,              \
               &Bs[pp][(h) * 8192 + 4096 + ldst]);                                    \
} while (0)

#define DSR(dst, a, OFF) \
    asm volatile("ds_read_b128 %0, %1 offset:%2" : "=v"(dst) : "v"(a), "n"(OFF) : "memory")

// A-quadrant mh (8 reads: rows wm*128+mh*64+[0,64)); immediate mh*8192 B = +64 rows
#define READ_A(pp, mh) do {                                                           \
    _Pragma("unroll") for (int i_ = 0; i_ < 4; ++i_) {                                \
        DSR(af[i_][0], aw[i_][0], (pp) * 32768 + (mh) * 8192);                        \
        DSR(af[i_][1], aw[i_][1], (pp) * 32768 + (mh) * 8192);                        \
    }                                                                                 \
} while (0)

// B-quadrant nh (4 reads: rows wn*64+nh*32+[0,32)); immediate nh*4096 B = +32 rows
#define READ_B(pp, nh) do {                                                           \
    _Pragma("unroll") for (int j_ = 0; j_ < 2; ++j_) {                                \
        DSR(bf[nh][j_][0], bw[j_][0], (pp) * 32768 + (nh) * 4096);                    \
        DSR(bf[nh][j_][1], bw[j_][1], (pp) * 32768 + (nh) * 4096);                    \
    }                                                                                 \
} while (0)

#define MFMA16(mh, nh)                                                                \
    _Pragma("unroll") for (int kk_ = 0; kk_ < 2; ++kk_)                               \
    _Pragma("unroll") for (int i_ = 0; i_ < 4; ++i_)                                  \
    _Pragma("unroll") for (int j_ = 0; j_ < 2; ++j_)                                  \
        acc[(mh) * 4 + i_][(nh) * 2 + j_] = __builtin_amdgcn_mfma_f32_16x16x32_f16(   \
            af[i_][kk_], bf[nh][j_][kk_], acc[(mh) * 4 + i_][(nh) * 2 + j_], 0, 0, 0)

#define LG(n) asm volatile("s_waitcnt lgkmcnt(" #n ")" ::: "memory")
#define VM(n) asm volatile("s_waitcnt vmcnt(" #n ")" ::: "memory")
#define BAR __builtin_amdgcn_s_barrier()
#define SB0 __builtin_amdgcn_sched_barrier(0)
#define PRIO1 __builtin_amdgcn_s_setprio(1)
#define PRIO0 __builtin_amdgcn_s_setprio(0)

#define TILE_FULL(p, kt) do {                                                         \
    /* ph0 */ STAGE_A2(p ^ 1, 0, (kt) + 1);                                           \
    BAR; LG(4); SB0; PRIO1; MFMA16(0, 0); PRIO0; SB0;                                 \
    /* ph1 */ STAGE_B(p ^ 1, 0, (kt) + 1); STAGE_B(p ^ 1, 1, (kt) + 1);               \
    VM(6); BAR; LG(0); SB0; PRIO1; MFMA16(0, 1); PRIO0; SB0;                          \
    READ_A(p, 1);                                                                     \
    /* ph2 */ STAGE_A2(p ^ 1, 1, (kt) + 1);                                           \
    BAR; LG(0); SB0; PRIO1; MFMA16(1, 0); PRIO0; SB0;                                 \
    /* ph3 */ VM(2); BAR; LG(0); SB0; PRIO1; MFMA16(1, 1); PRIO0; SB0;                \
    READ_A(p ^ 1, 0); READ_B(p ^ 1, 0); READ_B(p ^ 1, 1);                             \
} while (0)

// last tile (parity 1): no stages; drain A.1(NT-1) at ph1 with vmcnt(0)
#define TILE_LAST() do {                                                              \
    BAR; LG(4); SB0; PRIO1; MFMA16(0, 0); PRIO0; SB0;                                 \
    VM(0); BAR; LG(0); SB0; PRIO1; MFMA16(0, 1); PRIO0; SB0;                          \
    READ_A(1, 1);                                                                     \
    BAR; LG(0); SB0; PRIO1; MFMA16(1, 0); PRIO0; SB0;                                 \
    BAR; LG(0); SB0; PRIO1; MFMA16(1, 1); PRIO0; SB0;                                 \
} while (0)

template<int KDIM, int EPI>
__launch_bounds__(512, 2)
__global__ void gemm256(const _Float16* __restrict__ A,
                        const _Float16* __restrict__ B,
                        void* __restrict__ Cout) {
    constexpr int NT = KDIM / 64;                 // 32 (gemm1) / 22 (gemm2): even, >= 4
    __shared__ __align__(16) _Float16 As[2][16384];   // [buf][256 rows * 64 k-halves]
    __shared__ __align__(16) _Float16 Bs[2][16384];

    const int t = threadIdx.x;
    const int wave = t >> 6, lane = t & 63;
    const int id = blockIdx.x;
    const int m0 = (id & 63) * 256;               // 64 m-panels exactly; m fastest
    const int n_p = id >> 6;
    const int n0 = n_p * 256;
    const int wm = wave >> 2, wn = wave & 3;      // 2x4 wave grid; wave tile 128(M) x 64(N)
    const int q4 = lane >> 4, l15 = lane & 15;

    // staging: per-lane global source (pre-swizzled chunk), wave-uniform LDS dest
    const int srow = wave * 8 + (lane >> 3);
    const int schunk = (lane & 7) ^ (lane >> 3);
    const _Float16* ag = A + (size_t)(m0 + srow) * KDIM + schunk * 8;
    const _Float16* bg = B + (size_t)(n0 + srow) * KDIM + schunk * 8;
    const int ldst = wave * 512;                  // halves

    // LDS byte addresses for asm ds_read (swizzle: chunk c of row r at c^(r&7);
    // quadrant offsets are +64/+32 rows == 0 mod 8, so swizzle is offset-invariant)
    unsigned AsB = (unsigned)(uintptr_t)&As[0][0];
    unsigned BsB = (unsigned)(uintptr_t)&Bs[0][0];
    unsigned aw[4][2], bw[2][2];
#pragma unroll
    for (int i = 0; i < 4; ++i) {
        int rA = wm * 128 + i * 16 + l15;
        unsigned e = (unsigned)(rA * 64 + ((q4 ^ (rA & 7)) * 8)) * 2u;   // bytes
        aw[i][0] = AsB + e;
        aw[i][1] = AsB + (e ^ 64u);
    }
#pragma unroll
    for (int j = 0; j < 2; ++j) {
        int rB = wn * 64 + j * 16 + l15;
        unsigned e = (unsigned)(rB * 64 + ((q4 ^ (rB & 7)) * 8)) * 2u;
        bw[j][0] = BsB + e;
        bw[j][1] = BsB + (e ^ 64u);
    }

    floatx4 zero = {0.f, 0.f, 0.f, 0.f};
    floatx4 acc[8][4];
#pragma unroll
    for (int mi = 0; mi < 8; ++mi)
#pragma unroll
        for (int ni = 0; ni < 4; ++ni) acc[mi][ni] = zero;

    half8 af[4][2];        // current A quadrant frags
    half8 bf[2][2][2];     // [nh][frag][kk] — both B quadrants live

    // prologue: A.0(0), B0(0), B1(0), A.1(0); drain all but A.1(0)
    STAGE_A2(0, 0, 0);
    STAGE_B(0, 0, 0);
    STAGE_B(0, 1, 0);
    STAGE_A2(0, 1, 0);
    VM(2);                                        // A.0,B0,B1(0) published; A.1(0) in flight
    BAR;
    READ_A(0, 0); READ_B(0, 0); READ_B(0, 1);     // 16 reads, consumed in ph0/ph1

    for (int tt = 0; tt < NT - 2; tt += 2) {
        TILE_FULL(0, tt);
        TILE_FULL(1, tt + 1);
    }
    TILE_FULL(0, NT - 2);
    TILE_LAST();

    if constexpr (EPI == 1) {
        // ni 0,1 = gate, ni 2,3 = up of the same h-columns
        _Float16* hout = (_Float16*)Cout;
        const int rbase = m0 + wm * 128 + q4 * 4;
        const int colbase = (n_p * 4 + wn) * 32 + l15;
#pragma unroll
        for (int mi = 0; mi < 8; ++mi)
#pragma unroll
            for (int nc = 0; nc < 2; ++nc)
#pragma unroll
                for (int r = 0; r < 4; ++r) {
                    int row = rbase + mi * 16 + r;
                    int col = colbase + nc * 16;
                    float g = acc[mi][nc][r];
                    float u = acc[mi][nc + 2][r];
                    float s = (g / (1.0f + __expf(-g))) * u;
                    hout[(size_t)row * I_DIM + col] = (_Float16)s;
                }
    } else {
        float* outp = (float*)Cout;
        const int rbase = m0 + wm * 128 + q4 * 4;
#pragma unroll
        for (int mi = 0; mi < 8; ++mi)
#pragma unroll
            for (int ni = 0; ni < 4; ++ni)
#pragma unroll
                for (int r = 0; r < 4; ++r) {
                    int row = rbase + mi * 16 + r;
                    int col = n0 + wn * 64 + ni * 16 + l15;
                    outp[(size_t)row * H_DIM + col] = acc[mi][ni][r];
                }
    }
}

extern "C" void kernel_launch(void* const* d_in, const int* in_sizes, int n_in,
                              void* d_out, int out_size, void* d_ws, size_t ws_size,
                              hipStream_t stream) {
    const float* x    = (const float*)d_in[0];
    const int* qw_g   = (const int*)d_in[1];
    const int* qz_g   = (const int*)d_in[2];
    const float* sc_g = (const float*)d_in[3];
    const int* qw_u   = (const int*)d_in[4];
    const int* qz_u   = (const int*)d_in[5];
    const float* sc_u = (const float*)d_in[6];
    const int* qw_d   = (const int*)d_in[7];
    const int* qz_d   = (const int*)d_in[8];
    const float* sc_d = (const float*)d_in[9];
    float* out = (float*)d_out;

    // ws (fp16): xh 64MiB | h 44MiB | B' 11MiB | Wd_t 5.5MiB
    char* ws = (char*)d_ws;
    _Float16* xh  = (_Float16*)ws;  ws += (size_t)T_DIM * H_DIM * sizeof(_Float16);
    _Float16* hh  = (_Float16*)ws;  ws += (size_t)T_DIM * I_DIM * sizeof(_Float16);
    _Float16* Bgu = (_Float16*)ws;  ws += (size_t)NB_DIM * H_DIM * sizeof(_Float16);
    _Float16* Wd  = (_Float16*)ws;  ws += (size_t)I_DIM * H_DIM * sizeof(_Float16);

    cvt_fp16_kernel<<<(T_DIM * H_DIM) / 2048, 256, 0, stream>>>(x, xh);
    dequant_kernel<<<dim3(I_DIM / 64, H_DIM / 32), 256, 0, stream>>>(qw_g, qz_g, sc_g, Bgu, H_DIM, I_DIM, 1, 0);
    dequant_kernel<<<dim3(I_DIM / 64, H_DIM / 32), 256, 0, stream>>>(qw_u, qz_u, sc_u, Bgu, H_DIM, I_DIM, 1, 32);
    dequant_kernel<<<dim3(H_DIM / 64, I_DIM / 32), 256, 0, stream>>>(qw_d, qz_d, sc_d, Wd, I_DIM, H_DIM, 0, 0);
    gemm256<H_DIM, 1><<<(T_DIM / 256) * (NB_DIM / 256), 512, 0, stream>>>(xh, Bgu, hh);
    gemm256<I_DIM, 0><<<(T_DIM / 256) * (H_DIM / 256), 512, 0, stream>>>(hh, Wd, out);
}